// Round 5
// baseline (1237.460 us; speedup 1.0000x reference)
//
#include <hip/hip_runtime.h>
#include <cmath>

#define HH 512
#define WW 512
#define NB 8
#define CIN 4
#define C2 32
#define C3 16
#define CF 8
#define HW (HH*WW)      /* 262144 */
#define NPIX (NB*HW)    /* 2097152 */
#define NBC 2           /* batches per conv chunk (workspace-fitted) */

__device__ __forceinline__ float lrelu_f(float v){ return v < 0.f ? 0.2f*v : v; }
__device__ __forceinline__ int reflect_i(int i){ int r = i < 0 ? -i : i; return r >= HH ? 2*HH - 2 - r : r; }

// ---------------------------------------------------------------------------
// Conv 3x3 (zero pad=1, cross-correlation, OIHW weights). Thread = 4 adjacent
// pixels x 8 output channels. Weights/bias read via WAVE-UNIFORM indices ->
// s_load into SGPRs (scalar pipe), FMA uses the SGPR operand directly.
// No LDS at all: removes the LDS-issue bottleneck (round-4 post-mortem).
// ---------------------------------------------------------------------------
template<int Ci, int Co, bool LRELU>
__global__ __launch_bounds__(256) void k_conv(const float* __restrict__ in,
                                              const float* __restrict__ wgt,
                                              const float* __restrict__ bias,
                                              float* __restrict__ outp)
{
    constexpr int NG = Co/8;
    int t   = blockIdx.x*256 + threadIdx.x;
    int pix = t & 65535;
    int r   = t >> 16;          // uniform per block (256 | 65536)
    int cg  = r % NG;
    int b   = r / NG;
    int h   = pix >> 7;
    int w0  = (pix & 127) << 2;
    int co0 = cg*8;
    const float* inb = in + (size_t)b*Ci*HW;

    float acc[8][4];
    #pragma unroll
    for (int j=0;j<8;j++){
        float bv = bias[co0+j];              // uniform -> SGPR
        #pragma unroll
        for (int p=0;p<4;p++) acc[j][p] = bv;
    }

    #pragma unroll 1
    for (int ci=0; ci<Ci; ci++){
        float v[3][6];
        const float* inc = inb + (size_t)ci*HW;
        #pragma unroll
        for (int dy=0;dy<3;dy++){
            int hh = h + dy - 1;
            int hc = hh < 0 ? 0 : (hh > HH-1 ? HH-1 : hh);
            bool hok = (unsigned)hh < (unsigned)HH;
            #pragma unroll
            for (int dx=0;dx<6;dx++){
                int wx = w0 + dx - 1;
                int wc = wx < 0 ? 0 : (wx > WW-1 ? WW-1 : wx);
                float val = inc[hc*WW + wc];
                v[dy][dx] = (hok && (unsigned)wx < (unsigned)WW) ? val : 0.f;
            }
        }
        int wbase = (co0*Ci + ci)*9;         // uniform
        #pragma unroll
        for (int j=0;j<8;j++){
            float wj[9];
            #pragma unroll
            for (int q=0;q<9;q++) wj[q] = wgt[wbase + j*(Ci*9) + q];  // uniform -> s_load
            #pragma unroll
            for (int dy=0;dy<3;dy++){
                #pragma unroll
                for (int dx=0;dx<3;dx++){
                    float wv = wj[dy*3+dx];
                    #pragma unroll
                    for (int p=0;p<4;p++)
                        acc[j][p] = fmaf(v[dy][dx+p], wv, acc[j][p]);
                }
            }
        }
    }

    float* ob = outp + (size_t)b*Co*HW;
    #pragma unroll
    for (int j=0;j<8;j++){
        float4 o;
        o.x = LRELU ? lrelu_f(acc[j][0]) : acc[j][0];
        o.y = LRELU ? lrelu_f(acc[j][1]) : acc[j][1];
        o.z = LRELU ? lrelu_f(acc[j][2]) : acc[j][2];
        o.w = LRELU ? lrelu_f(acc[j][3]) : acc[j][3];
        *(float4*)(ob + (size_t)(co0+j)*HW + h*WW + w0) = o;
    }
}

// ---------------------------------------------------------------------------
// Vertical box pass: thread walks a column chunk with register sliding window.
// ---------------------------------------------------------------------------
template<int WS>
__global__ __launch_bounds__(256) void k_vbox(const float* __restrict__ f,
                                              float* __restrict__ vs,
                                              float* __restrict__ vq)
{
    constexpr int P = WS/2;
    constexpr int CH = 64;
    int bid   = blockIdx.x;
    int wb    = bid & 1;
    int hc    = (bid >> 1) & 7;
    int plane = bid >> 4;
    int w     = wb*256 + threadIdx.x;
    int h0    = hc*CH;
    const float* base = f  + (size_t)plane*HW + w;
    float*       os   = vs + (size_t)plane*HW + w;
    float*       oq   = vq + (size_t)plane*HW + w;

    float s = 0.f, q = 0.f;
    #pragma unroll
    for (int dy = -P; dy <= P; dy++){
        float v = base[(size_t)reflect_i(h0+dy)*WW];
        s += v; q = fmaf(v, v, q);
    }
    #pragma unroll 4
    for (int h = h0; h < h0+CH; h++){
        os[(size_t)h*WW] = s;
        oq[(size_t)h*WW] = q;
        float e = base[(size_t)reflect_i(h+1+P)*WW];
        float l = base[(size_t)reflect_i(h-P)*WW];
        s += e - l;
        q = fmaf(e, e, q);
        q = fmaf(-l, l, q);
    }
}

// ---------------------------------------------------------------------------
// Horizontal box pass + var/sqrt/channel-sum/pow0.8 + fused accumulate.
// ---------------------------------------------------------------------------
__device__ __forceinline__ int swz_i(int j){ return j + (j >> 4); }

template<int WS>
__global__ __launch_bounds__(256) void k_hbox(const float* __restrict__ vs,
                                              const float* __restrict__ vq,
                                              float* __restrict__ fused,
                                              const float* __restrict__ fwv, int sidx)
{
    constexpr int P   = WS/2;
    constexpr int L   = WW + 2*P;
    constexpr int SWL = L + (L >> 4) + 2;
    constexpr float inv = 1.f/((float)WS*(float)WS);
    __shared__ float sv[CF*SWL];
    __shared__ float sq[CF*SWL];

    int bid = blockIdx.x;
    int row = bid & (HH-1);
    int bb  = bid >> 9;
    const float* vsb = vs + ((size_t)bb*CF*HH + row)*WW;
    const float* vqb = vq + ((size_t)bb*CF*HH + row)*WW;

    for (int i = threadIdx.x; i < CF*L; i += 256){
        int c = i / L, j = i - c*L;
        int s = j - P; s = s < 0 ? -s : (s > WW-1 ? 2*WW-2 - s : s);
        sv[c*SWL + swz_i(j)] = vsb[(size_t)c*HW + s];
        sq[c*SWL + swz_i(j)] = vqb[(size_t)c*HW + s];
    }
    __syncthreads();

    int c = threadIdx.x >> 5;
    int g = threadIdx.x & 31;
    const float* pv = sv + c*SWL;
    const float* pq = sq + c*SWL;
    int bofs = 17*g;

    float S = 0.f, Q = 0.f;
    #pragma unroll
    for (int k = 0; k < WS; k++){
        S += pv[bofs + k + (k>>4)];
        Q += pq[bofs + k + (k>>4)];
    }
    float res[16];
    #pragma unroll
    for (int k = 0; k < 16; k++){
        float m  = S*inv;
        float m2 = Q*inv;
        float var = fmaxf(fmaf(-m, m, m2), 1e-6f);
        res[k] = sqrtf(var);
        if (k < 15){
            S += pv[bofs + (k+WS) + ((k+WS)>>4)] - pv[bofs + k + (k>>4)];
            Q += pq[bofs + (k+WS) + ((k+WS)>>4)] - pq[bofs + k + (k>>4)];
        }
    }
    __syncthreads();
    #pragma unroll
    for (int k = 0; k < 16; k++) sv[c*SWL + bofs + k + (k>>4)] = res[k];
    __syncthreads();

    float fwb = fwv[sidx];
    #pragma unroll
    for (int half = 0; half < 2; half++){
        int col = threadIdx.x + half*256;
        float a = 0.f;
        #pragma unroll
        for (int cc = 0; cc < CF; cc++) a += sv[cc*SWL + swz_i(col)];
        float val = powf(a*0.125f, 0.8f);
        fused[((size_t)bb*HH + row)*WW + col] += fwb*val;
    }
}

// ---------------------------------------------------------------------------
// Exact quantiles: 3-level radix (8/8/16 bits), LDS-privatized hot levels.
// ---------------------------------------------------------------------------
__global__ void k_h8(const float* __restrict__ fused, const float* __restrict__ fb,
                     unsigned* __restrict__ hist8)
{
    __shared__ unsigned lh[256];
    lh[threadIdx.x] = 0;
    __syncthreads();
    float fbv = fb[0];
    int i = blockIdx.x*256 + threadIdx.x;
    int stride = gridDim.x*256;
    for (; i < NPIX; i += stride){
        float v = fmaxf(fused[i] + fbv, 0.f);
        atomicAdd(&lh[__float_as_uint(v) >> 24], 1u);
    }
    __syncthreads();
    if (lh[threadIdx.x]) atomicAdd(&hist8[threadIdx.x], lh[threadIdx.x]);
}

__global__ void k_scan8(const unsigned* __restrict__ hist8,
                        int* __restrict__ cand8, int* __restrict__ rank8)
{
    if (threadIdx.x == 0){
        const unsigned RK[4] = {524287u, 524288u, 1572863u, 1572864u};
        unsigned cum = 0; int qi = 0;
        for (int b = 0; b < 256 && qi < 4; b++){
            unsigned cnt = hist8[b];
            while (qi < 4 && RK[qi] < cum + cnt){
                cand8[qi] = b; rank8[qi] = (int)(RK[qi] - cum); qi++;
            }
            cum += cnt;
        }
    }
}

__global__ void k_h8b(const float* __restrict__ fused, const float* __restrict__ fb,
                      const int* __restrict__ cand8, unsigned* __restrict__ hist8b)
{
    __shared__ unsigned lh[1024];
    for (int i = threadIdx.x; i < 1024; i += 256) lh[i] = 0;
    __syncthreads();
    float fbv = fb[0];
    int c0 = cand8[0], c1 = cand8[1], c2 = cand8[2], c3 = cand8[3];
    bool d1 = (c1 != c0);
    bool d2 = (c2 != c0) && (c2 != c1);
    bool d3 = (c3 != c0) && (c3 != c1) && (c3 != c2);
    int i = blockIdx.x*256 + threadIdx.x;
    int stride = gridDim.x*256;
    for (; i < NPIX; i += stride){
        unsigned u = __float_as_uint(fmaxf(fused[i] + fbv, 0.f));
        int hi = (int)(u >> 24);
        unsigned mid = (u >> 16) & 0xffu;
        if (hi == c0)       atomicAdd(&lh[mid],       1u);
        if (d1 && hi == c1) atomicAdd(&lh[256u+mid],  1u);
        if (d2 && hi == c2) atomicAdd(&lh[512u+mid],  1u);
        if (d3 && hi == c3) atomicAdd(&lh[768u+mid],  1u);
    }
    __syncthreads();
    for (int i = threadIdx.x; i < 1024; i += 256)
        if (lh[i]) atomicAdd(&hist8b[i], lh[i]);
}

__global__ void k_scan8b(const unsigned* __restrict__ hist8b,
                         const int* __restrict__ cand8, const int* __restrict__ rank8,
                         int* __restrict__ cand16, int* __restrict__ rank16)
{
    int qi = threadIdx.x;
    if (qi < 4){
        int slot = qi;
        for (int j = 0; j < qi; j++) if (cand8[j] == cand8[qi]){ slot = j; break; }
        const unsigned* h = hist8b + slot*256;
        unsigned k = (unsigned)rank8[qi], cum = 0;
        for (int b = 0; b < 256; b++){
            unsigned cnt = h[b];
            if (cnt && k >= cum && k < cum + cnt){
                cand16[qi] = (cand8[qi] << 8) | b;
                rank16[qi] = (int)(k - cum);
            }
            cum += cnt;
        }
    }
}

__global__ void k_h16(const float* __restrict__ fused, const float* __restrict__ fb,
                      const int* __restrict__ cand16, unsigned* __restrict__ histlo)
{
    float fbv = fb[0];
    int c0 = cand16[0], c1 = cand16[1], c2 = cand16[2], c3 = cand16[3];
    bool d1 = (c1 != c0);
    bool d2 = (c2 != c0) && (c2 != c1);
    bool d3 = (c3 != c0) && (c3 != c1) && (c3 != c2);
    int i = blockIdx.x*256 + threadIdx.x;
    int stride = gridDim.x*256;
    for (; i < NPIX; i += stride){
        unsigned u = __float_as_uint(fmaxf(fused[i] + fbv, 0.f));
        int hi = (int)(u >> 16);
        unsigned lo = u & 0xffffu;
        if (hi == c0)       atomicAdd(&histlo[lo],           1u);
        if (d1 && hi == c1) atomicAdd(&histlo[65536u + lo],  1u);
        if (d2 && hi == c2) atomicAdd(&histlo[131072u + lo], 1u);
        if (d3 && hi == c3) atomicAdd(&histlo[196608u + lo], 1u);
    }
}

__global__ void k_scan16(const unsigned* __restrict__ histlo,
                         const int* __restrict__ cand16, const int* __restrict__ rank16,
                         float* __restrict__ ostat)
{
    int qi = blockIdx.x;
    int slot = qi;
    for (int j = 0; j < qi; j++) if (cand16[j] == cand16[qi]){ slot = j; break; }
    const unsigned* hist = histlo + (size_t)slot*65536;
    __shared__ unsigned csum[256];
    __shared__ unsigned cbase[256];
    int t = threadIdx.x;
    unsigned s = 0;
    for (int i = 0; i < 256; i++) s += hist[t*256 + i];
    csum[t] = s;
    __syncthreads();
    if (t == 0){ unsigned run = 0; for (int i = 0; i < 256; i++){ cbase[i] = run; run += csum[i]; } }
    __syncthreads();
    unsigned k = (unsigned)rank16[qi];
    unsigned cum = cbase[t];
    for (int i = 0; i < 256; i++){
        unsigned cnt = hist[t*256 + i];
        if (cnt && k >= cum && k < cum + cnt)
            ostat[qi] = __uint_as_float(((unsigned)cand16[qi] << 16) | (unsigned)(t*256 + i));
        cum += cnt;
    }
}

// ---------------------------------------------------------------------------
// Global per-(b,c) std of x, ddof=1, double partial sums (deterministic).
// ---------------------------------------------------------------------------
__global__ void k_gstd_part(const float* __restrict__ x, double* __restrict__ part)
{
    int bid = blockIdx.x;
    int plane = bid >> 3, chunk = bid & 7;
    const float4* p4 = (const float4*)(x + (size_t)plane*HW + (size_t)chunk*32768);
    int t = threadIdx.x;
    double s=0.0, s2=0.0;
    for (int k=0;k<32;k++){
        float4 v = p4[k*256 + t];
        s  += (double)v.x + (double)v.y + (double)v.z + (double)v.w;
        s2 += (double)v.x*v.x + (double)v.y*v.y + (double)v.z*v.z + (double)v.w*v.w;
    }
    __shared__ double rs[256], rq[256];
    rs[t]=s; rq[t]=s2; __syncthreads();
    for (int off=128; off>0; off>>=1){
        if (t<off){ rs[t]+=rs[t+off]; rq[t]+=rq[t+off]; }
        __syncthreads();
    }
    if (t==0){ part[bid*2]=rs[0]; part[bid*2+1]=rq[0]; }
}

__global__ void k_gstd_final(const double* __restrict__ part, float* __restrict__ gstd)
{
    int t = threadIdx.x;
    if (t < 32){
        double s=0.0, s2=0.0;
        for (int j=0;j<8;j++){ s += part[(t*8+j)*2]; s2 += part[(t*8+j)*2+1]; }
        const double N = 262144.0;
        double var = (s2 - s*s/N) / (N - 1.0);
        gstd[t] = (float)sqrt(var < 0.0 ? 0.0 : var);
    }
}

__global__ void k_finalize(const float* __restrict__ ostat, const float* __restrict__ gstd,
                           const float* __restrict__ cwin, float* __restrict__ lov, float* __restrict__ hiv)
{
    int t = threadIdx.x;
    if (t < 32){
        float q25 = ostat[0] + 0.75f*(ostat[1]-ostat[0]);
        float q75 = ostat[2] + 0.25f*(ostat[3]-ostat[2]);
        float iqr = q75 - q25;
        float lo_b = q25 - 0.5f*iqr, hi_b = q75 + 0.5f*iqr;
        int c = t & 3;
        float m = fmaxf(fmaxf(cwin[0],cwin[1]), fmaxf(cwin[2],cwin[3]));
        float e0 = expf(cwin[0]-m), e1 = expf(cwin[1]-m), e2 = expf(cwin[2]-m), e3 = expf(cwin[3]-m);
        float smc = expf(cwin[c]-m) / (e0+e1+e2+e3);
        float g  = gstd[t];
        float gf = fminf(fmaxf(g*5.f, 0.5f), 2.f);
        float cf = fminf(fmaxf(smc*g*2.f, 0.8f), 1.2f);
        lov[t] = lo_b*gf*cf;
        hiv[t] = hi_b*gf*cf;
    }
}

__global__ void k_mask(const float* __restrict__ fused_in, const float* __restrict__ fb,
                       const float* __restrict__ lov, const float* __restrict__ hiv,
                       float* __restrict__ outp)
{
    int i = blockIdx.x*256 + threadIdx.x;
    float F = fmaxf(fused_in[i] + fb[0], 0.f);
    int b = i >> 18;
    float o = 0.f;
    #pragma unroll
    for (int c=0;c<4;c++){
        float lo = lov[b*4+c], hi = hiv[b*4+c];
        float n = (F - lo) / (hi - lo);
        n = fminf(fmaxf(n, 0.f), 1.f);
        o += 1.f/(1.f + expf(3.f - 6.f*n));
    }
    outp[i] = 0.25f * o;
}

// ---------------------------------------------------------------------------
extern "C" void kernel_launch(void* const* d_in, const int* in_sizes, int n_in,
                              void* d_out, int out_size, void* d_ws, size_t ws_size,
                              hipStream_t stream)
{
    const float* x  = (const float*)d_in[0];
    const float* w1 = (const float*)d_in[1];
    const float* b1 = (const float*)d_in[2];
    const float* w2 = (const float*)d_in[3];
    const float* b2 = (const float*)d_in[4];
    const float* w3 = (const float*)d_in[5];
    const float* b3 = (const float*)d_in[6];
    const float* fw = (const float*)d_in[7];
    const float* fb = (const float*)d_in[8];
    const float* cw = (const float*)d_in[9];
    float* out = (float*)d_out;
    char* ws = (char*)d_ws;

    size_t off = 0;
    auto take = [&](size_t bytes)->size_t{ size_t o = off; off += (bytes + 255) & ~(size_t)255; return o; };
    size_t o_f      = take((size_t)NB*CF*HW*4);     // conv3 output (64 MB)
    size_t o_h8     = take(256*4);
    size_t o_h8b    = take(1024*4);
    size_t o_histlo = take((size_t)4*65536*4);
    size_t o_c8     = take(4*4);
    size_t o_r8     = take(4*4);
    size_t o_c16    = take(4*4);
    size_t o_r16    = take(4*4);
    size_t o_os     = take(4*4);
    size_t o_part   = take(512*8);
    size_t o_gs     = take(32*4);
    size_t o_lo     = take(32*4);
    size_t o_hi     = take(32*4);
    // 128 MB region: f1+f2 chunks during convs, then vs+vq during boxes
    size_t o_R      = take((size_t)NB*CF*HW*4*2);

    float*    fbuf   = (float*)(ws + o_f);
    float*    f1     = (float*)(ws + o_R);                      // 64 MB (NBC=2 x 32ch)
    float*    f2     = f1 + (size_t)NBC*C2*HW;                  // 32 MB (NBC=2 x 16ch)
    float*    vsb    = (float*)(ws + o_R);
    float*    vqb    = vsb + (size_t)NB*CF*HW;
    unsigned* hist8  = (unsigned*)(ws + o_h8);
    unsigned* hist8b = (unsigned*)(ws + o_h8b);
    unsigned* histlo = (unsigned*)(ws + o_histlo);
    int*      c8     = (int*)(ws + o_c8);
    int*      r8     = (int*)(ws + o_r8);
    int*      c16    = (int*)(ws + o_c16);
    int*      r16    = (int*)(ws + o_r16);
    float*    osv    = (float*)(ws + o_os);
    double*   part   = (double*)(ws + o_part);
    float*    gs     = (float*)(ws + o_gs);
    float*    lov    = (float*)(ws + o_lo);
    float*    hiv    = (float*)(ws + o_hi);

    // --- conv stack, NBC batches per chunk, SGPR-weight kernels ---
    for (int ck = 0; ck < NB/NBC; ck++){
        const float* xb = x    + (size_t)ck*NBC*CIN*HW;
        float*       fo = fbuf + (size_t)ck*NBC*CF*HW;
        k_conv<CIN,C2,true ><<<NBC*1024,256,0,stream>>>(xb, w1, b1, f1);
        k_conv<C2, C3,true ><<<NBC*512, 256,0,stream>>>(f1, w2, b2, f2);
        k_conv<C3, CF,false><<<NBC*256, 256,0,stream>>>(f2, w3, b3, fo);
    }

    // --- global stds (independent of conv chain) ---
    k_gstd_part<<<256,256,0,stream>>>(x, part);
    k_gstd_final<<<1,256,0,stream>>>(part, gs);

    // --- multi-scale std maps (conv region dead -> vs/vq alias it) ---
    hipMemsetAsync(out, 0, (size_t)NPIX*4, stream);
    const int vgrid = NB*CF*16, hgrid = NB*512;
    k_vbox<11><<<vgrid,256,0,stream>>>(fbuf, vsb, vqb);
    k_hbox<11><<<hgrid,256,0,stream>>>(vsb, vqb, out, fw, 0);
    k_vbox<25><<<vgrid,256,0,stream>>>(fbuf, vsb, vqb);
    k_hbox<25><<<hgrid,256,0,stream>>>(vsb, vqb, out, fw, 1);
    k_vbox<49><<<vgrid,256,0,stream>>>(fbuf, vsb, vqb);
    k_hbox<49><<<hgrid,256,0,stream>>>(vsb, vqb, out, fw, 2);

    // --- exact quantiles ---
    hipMemsetAsync(hist8,  0, 256*4,  stream);
    hipMemsetAsync(hist8b, 0, 1024*4, stream);
    hipMemsetAsync(histlo, 0, (size_t)4*65536*4, stream);
    k_h8    <<<2048,256,0,stream>>>(out, fb, hist8);
    k_scan8 <<<1,64,0,stream>>>(hist8, c8, r8);
    k_h8b   <<<2048,256,0,stream>>>(out, fb, c8, hist8b);
    k_scan8b<<<1,64,0,stream>>>(hist8b, c8, r8, c16, r16);
    k_h16   <<<2048,256,0,stream>>>(out, fb, c16, histlo);
    k_scan16<<<4,256,0,stream>>>(histlo, c16, r16, osv);

    // --- thresholds + mask (in-place on d_out) ---
    k_finalize<<<1,64,0,stream>>>(osv, gs, cw, lov, hiv);
    k_mask<<<NPIX/256,256,0,stream>>>(out, fb, lov, hiv, out);
}

// Round 6
// 916.706 us; speedup vs baseline: 1.3499x; 1.3499x over previous
//
#include <hip/hip_runtime.h>
#include <cmath>

#define HH 512
#define WW 512
#define NB 8
#define CIN 4
#define C2 32
#define C3 16
#define CF 8
#define HW (HH*WW)      /* 262144 */
#define NPIX (NB*HW)    /* 2097152 */
#define NBC 2           /* batches per conv chunk (workspace-fitted) */

__device__ __forceinline__ float lrelu_f(float v){ return v < 0.f ? 0.2f*v : v; }
__device__ __forceinline__ int reflect_i(int i){ int r = i < 0 ? -i : i; return r >= HH ? 2*HH - 2 - r : r; }

// ---------------------------------------------------------------------------
// Conv 3x3 (zero pad=1, OIHW). Thread = 2 rows x 4 cols x 8 oc (8 px).
// Weights in LDS (uniform-index -> broadcast ds_read, conflict-free).
// Doubling px/thread halves weight-read + window-load cost per FMA vs the
// round-3 4px kernel (which sat at 49% VALUBusy). Block covers 16r x 128c.
// ---------------------------------------------------------------------------
template<int Ci, int Co, bool LRELU>
__global__ __launch_bounds__(256) void k_conv8(const float* __restrict__ in,
                                               const float* __restrict__ wgt,
                                               const float* __restrict__ bias,
                                               float* __restrict__ outp)
{
    constexpr int NG = Co/8;
    __shared__ float wl[Co*Ci*9];
    __shared__ float bl[Co];
    for (int i = threadIdx.x; i < Co*Ci*9; i += 256) wl[i] = wgt[i];
    if (threadIdx.x < Co) bl[threadIdx.x] = bias[threadIdx.x];
    __syncthreads();

    int bid   = blockIdx.x;
    int local = bid % (NG*128);
    int b     = bid / (NG*128);
    int cb    = local & 3;            // 4 col-blocks of 128
    int rb    = (local >> 2) & 31;    // 32 row-blocks of 16
    int cg    = local >> 7;           // oc group
    int tid   = threadIdx.x;
    int col   = cb*128 + (tid & 31)*4;
    int row0  = rb*16  + (tid >> 5)*2;
    int co0   = cg*8;
    const float* inb = in + (size_t)b*Ci*HW;

    float acc[8][2][4];
    #pragma unroll
    for (int j=0;j<8;j++){
        float bv = bl[co0+j];
        #pragma unroll
        for (int r=0;r<2;r++)
            #pragma unroll
            for (int p=0;p<4;p++) acc[j][r][p] = bv;
    }

    #pragma unroll 2
    for (int ci=0; ci<Ci; ci++){
        float v[4][6];
        const float* inc = inb + (size_t)ci*HW;
        #pragma unroll
        for (int dy=0;dy<4;dy++){
            int hh = row0 + dy - 1;
            int hc = hh < 0 ? 0 : (hh > HH-1 ? HH-1 : hh);
            bool hok = (unsigned)hh < (unsigned)HH;
            #pragma unroll
            for (int dx=0;dx<6;dx++){
                int wx = col + dx - 1;
                int wc = wx < 0 ? 0 : (wx > WW-1 ? WW-1 : wx);
                float val = inc[hc*WW + wc];
                v[dy][dx] = (hok && (unsigned)wx < (unsigned)WW) ? val : 0.f;
            }
        }
        #pragma unroll
        for (int j=0;j<8;j++){
            const float* wr = &wl[((co0+j)*Ci + ci)*9];
            float wj[9];
            #pragma unroll
            for (int q=0;q<9;q++) wj[q] = wr[q];
            #pragma unroll
            for (int dy=0;dy<3;dy++){
                #pragma unroll
                for (int dx=0;dx<3;dx++){
                    float wv = wj[dy*3+dx];
                    #pragma unroll
                    for (int r=0;r<2;r++)
                        #pragma unroll
                        for (int p=0;p<4;p++)
                            acc[j][r][p] = fmaf(v[dy+r][dx+p], wv, acc[j][r][p]);
                }
            }
        }
    }

    float* ob = outp + (size_t)b*Co*HW;
    #pragma unroll
    for (int j=0;j<8;j++){
        #pragma unroll
        for (int r=0;r<2;r++){
            float4 o;
            o.x = LRELU ? lrelu_f(acc[j][r][0]) : acc[j][r][0];
            o.y = LRELU ? lrelu_f(acc[j][r][1]) : acc[j][r][1];
            o.z = LRELU ? lrelu_f(acc[j][r][2]) : acc[j][r][2];
            o.w = LRELU ? lrelu_f(acc[j][r][3]) : acc[j][r][3];
            *(float4*)(ob + (size_t)(co0+j)*HW + (size_t)(row0+r)*WW + col) = o;
        }
    }
}

// ---------------------------------------------------------------------------
// Vertical box pass: thread walks a column chunk with register sliding window.
// ---------------------------------------------------------------------------
template<int WS>
__global__ __launch_bounds__(256) void k_vbox(const float* __restrict__ f,
                                              float* __restrict__ vs,
                                              float* __restrict__ vq)
{
    constexpr int P = WS/2;
    constexpr int CH = 64;
    int bid   = blockIdx.x;
    int wb    = bid & 1;
    int hc    = (bid >> 1) & 7;
    int plane = bid >> 4;
    int w     = wb*256 + threadIdx.x;
    int h0    = hc*CH;
    const float* base = f  + (size_t)plane*HW + w;
    float*       os   = vs + (size_t)plane*HW + w;
    float*       oq   = vq + (size_t)plane*HW + w;

    float s = 0.f, q = 0.f;
    #pragma unroll
    for (int dy = -P; dy <= P; dy++){
        float v = base[(size_t)reflect_i(h0+dy)*WW];
        s += v; q = fmaf(v, v, q);
    }
    #pragma unroll 4
    for (int h = h0; h < h0+CH; h++){
        os[(size_t)h*WW] = s;
        oq[(size_t)h*WW] = q;
        float e = base[(size_t)reflect_i(h+1+P)*WW];
        float l = base[(size_t)reflect_i(h-P)*WW];
        s += e - l;
        q = fmaf(e, e, q);
        q = fmaf(-l, l, q);
    }
}

// ---------------------------------------------------------------------------
// Horizontal box pass + var/sqrt/channel-sum/pow0.8 + fused accumulate.
// ---------------------------------------------------------------------------
__device__ __forceinline__ int swz_i(int j){ return j + (j >> 4); }

template<int WS>
__global__ __launch_bounds__(256) void k_hbox(const float* __restrict__ vs,
                                              const float* __restrict__ vq,
                                              float* __restrict__ fused,
                                              const float* __restrict__ fwv, int sidx)
{
    constexpr int P   = WS/2;
    constexpr int L   = WW + 2*P;
    constexpr int SWL = L + (L >> 4) + 2;
    constexpr float inv = 1.f/((float)WS*(float)WS);
    __shared__ float sv[CF*SWL];
    __shared__ float sq[CF*SWL];

    int bid = blockIdx.x;
    int row = bid & (HH-1);
    int bb  = bid >> 9;
    const float* vsb = vs + ((size_t)bb*CF*HH + row)*WW;
    const float* vqb = vq + ((size_t)bb*CF*HH + row)*WW;

    for (int i = threadIdx.x; i < CF*L; i += 256){
        int c = i / L, j = i - c*L;
        int s = j - P; s = s < 0 ? -s : (s > WW-1 ? 2*WW-2 - s : s);
        sv[c*SWL + swz_i(j)] = vsb[(size_t)c*HW + s];
        sq[c*SWL + swz_i(j)] = vqb[(size_t)c*HW + s];
    }
    __syncthreads();

    int c = threadIdx.x >> 5;
    int g = threadIdx.x & 31;
    const float* pv = sv + c*SWL;
    const float* pq = sq + c*SWL;
    int bofs = 17*g;

    float S = 0.f, Q = 0.f;
    #pragma unroll
    for (int k = 0; k < WS; k++){
        S += pv[bofs + k + (k>>4)];
        Q += pq[bofs + k + (k>>4)];
    }
    float res[16];
    #pragma unroll
    for (int k = 0; k < 16; k++){
        float m  = S*inv;
        float m2 = Q*inv;
        float var = fmaxf(fmaf(-m, m, m2), 1e-6f);
        res[k] = sqrtf(var);
        if (k < 15){
            S += pv[bofs + (k+WS) + ((k+WS)>>4)] - pv[bofs + k + (k>>4)];
            Q += pq[bofs + (k+WS) + ((k+WS)>>4)] - pq[bofs + k + (k>>4)];
        }
    }
    __syncthreads();
    #pragma unroll
    for (int k = 0; k < 16; k++) sv[c*SWL + bofs + k + (k>>4)] = res[k];
    __syncthreads();

    float fwb = fwv[sidx];
    #pragma unroll
    for (int half = 0; half < 2; half++){
        int col = threadIdx.x + half*256;
        float a = 0.f;
        #pragma unroll
        for (int cc = 0; cc < CF; cc++) a += sv[cc*SWL + swz_i(col)];
        float val = powf(a*0.125f, 0.8f);
        fused[((size_t)bb*HH + row)*WW + col] += fwb*val;
    }
}

// ---------------------------------------------------------------------------
// Exact quantiles: 3-level radix (8/8/16 bits), LDS-privatized hot levels.
// ---------------------------------------------------------------------------
__global__ void k_h8(const float* __restrict__ fused, const float* __restrict__ fb,
                     unsigned* __restrict__ hist8)
{
    __shared__ unsigned lh[256];
    lh[threadIdx.x] = 0;
    __syncthreads();
    float fbv = fb[0];
    int i = blockIdx.x*256 + threadIdx.x;
    int stride = gridDim.x*256;
    for (; i < NPIX; i += stride){
        float v = fmaxf(fused[i] + fbv, 0.f);
        atomicAdd(&lh[__float_as_uint(v) >> 24], 1u);
    }
    __syncthreads();
    if (lh[threadIdx.x]) atomicAdd(&hist8[threadIdx.x], lh[threadIdx.x]);
}

__global__ void k_scan8(const unsigned* __restrict__ hist8,
                        int* __restrict__ cand8, int* __restrict__ rank8)
{
    if (threadIdx.x == 0){
        const unsigned RK[4] = {524287u, 524288u, 1572863u, 1572864u};
        unsigned cum = 0; int qi = 0;
        for (int b = 0; b < 256 && qi < 4; b++){
            unsigned cnt = hist8[b];
            while (qi < 4 && RK[qi] < cum + cnt){
                cand8[qi] = b; rank8[qi] = (int)(RK[qi] - cum); qi++;
            }
            cum += cnt;
        }
    }
}

__global__ void k_h8b(const float* __restrict__ fused, const float* __restrict__ fb,
                      const int* __restrict__ cand8, unsigned* __restrict__ hist8b)
{
    __shared__ unsigned lh[1024];
    for (int i = threadIdx.x; i < 1024; i += 256) lh[i] = 0;
    __syncthreads();
    float fbv = fb[0];
    int c0 = cand8[0], c1 = cand8[1], c2 = cand8[2], c3 = cand8[3];
    bool d1 = (c1 != c0);
    bool d2 = (c2 != c0) && (c2 != c1);
    bool d3 = (c3 != c0) && (c3 != c1) && (c3 != c2);
    int i = blockIdx.x*256 + threadIdx.x;
    int stride = gridDim.x*256;
    for (; i < NPIX; i += stride){
        unsigned u = __float_as_uint(fmaxf(fused[i] + fbv, 0.f));
        int hi = (int)(u >> 24);
        unsigned mid = (u >> 16) & 0xffu;
        if (hi == c0)       atomicAdd(&lh[mid],       1u);
        if (d1 && hi == c1) atomicAdd(&lh[256u+mid],  1u);
        if (d2 && hi == c2) atomicAdd(&lh[512u+mid],  1u);
        if (d3 && hi == c3) atomicAdd(&lh[768u+mid],  1u);
    }
    __syncthreads();
    for (int i = threadIdx.x; i < 1024; i += 256)
        if (lh[i]) atomicAdd(&hist8b[i], lh[i]);
}

__global__ void k_scan8b(const unsigned* __restrict__ hist8b,
                         const int* __restrict__ cand8, const int* __restrict__ rank8,
                         int* __restrict__ cand16, int* __restrict__ rank16)
{
    int qi = threadIdx.x;
    if (qi < 4){
        int slot = qi;
        for (int j = 0; j < qi; j++) if (cand8[j] == cand8[qi]){ slot = j; break; }
        const unsigned* h = hist8b + slot*256;
        unsigned k = (unsigned)rank8[qi], cum = 0;
        for (int b = 0; b < 256; b++){
            unsigned cnt = h[b];
            if (cnt && k >= cum && k < cum + cnt){
                cand16[qi] = (cand8[qi] << 8) | b;
                rank16[qi] = (int)(k - cum);
            }
            cum += cnt;
        }
    }
}

__global__ void k_h16(const float* __restrict__ fused, const float* __restrict__ fb,
                      const int* __restrict__ cand16, unsigned* __restrict__ histlo)
{
    float fbv = fb[0];
    int c0 = cand16[0], c1 = cand16[1], c2 = cand16[2], c3 = cand16[3];
    bool d1 = (c1 != c0);
    bool d2 = (c2 != c0) && (c2 != c1);
    bool d3 = (c3 != c0) && (c3 != c1) && (c3 != c2);
    int i = blockIdx.x*256 + threadIdx.x;
    int stride = gridDim.x*256;
    for (; i < NPIX; i += stride){
        unsigned u = __float_as_uint(fmaxf(fused[i] + fbv, 0.f));
        int hi = (int)(u >> 16);
        unsigned lo = u & 0xffffu;
        if (hi == c0)       atomicAdd(&histlo[lo],           1u);
        if (d1 && hi == c1) atomicAdd(&histlo[65536u + lo],  1u);
        if (d2 && hi == c2) atomicAdd(&histlo[131072u + lo], 1u);
        if (d3 && hi == c3) atomicAdd(&histlo[196608u + lo], 1u);
    }
}

__global__ void k_scan16(const unsigned* __restrict__ histlo,
                         const int* __restrict__ cand16, const int* __restrict__ rank16,
                         float* __restrict__ ostat)
{
    int qi = blockIdx.x;
    int slot = qi;
    for (int j = 0; j < qi; j++) if (cand16[j] == cand16[qi]){ slot = j; break; }
    const unsigned* hist = histlo + (size_t)slot*65536;
    __shared__ unsigned csum[256];
    __shared__ unsigned cbase[256];
    int t = threadIdx.x;
    unsigned s = 0;
    for (int i = 0; i < 256; i++) s += hist[t*256 + i];
    csum[t] = s;
    __syncthreads();
    if (t == 0){ unsigned run = 0; for (int i = 0; i < 256; i++){ cbase[i] = run; run += csum[i]; } }
    __syncthreads();
    unsigned k = (unsigned)rank16[qi];
    unsigned cum = cbase[t];
    for (int i = 0; i < 256; i++){
        unsigned cnt = hist[t*256 + i];
        if (cnt && k >= cum && k < cum + cnt)
            ostat[qi] = __uint_as_float(((unsigned)cand16[qi] << 16) | (unsigned)(t*256 + i));
        cum += cnt;
    }
}

// ---------------------------------------------------------------------------
// Global per-(b,c) std of x, ddof=1, double partial sums (deterministic).
// ---------------------------------------------------------------------------
__global__ void k_gstd_part(const float* __restrict__ x, double* __restrict__ part)
{
    int bid = blockIdx.x;
    int plane = bid >> 3, chunk = bid & 7;
    const float4* p4 = (const float4*)(x + (size_t)plane*HW + (size_t)chunk*32768);
    int t = threadIdx.x;
    double s=0.0, s2=0.0;
    for (int k=0;k<32;k++){
        float4 v = p4[k*256 + t];
        s  += (double)v.x + (double)v.y + (double)v.z + (double)v.w;
        s2 += (double)v.x*v.x + (double)v.y*v.y + (double)v.z*v.z + (double)v.w*v.w;
    }
    __shared__ double rs[256], rq[256];
    rs[t]=s; rq[t]=s2; __syncthreads();
    for (int off=128; off>0; off>>=1){
        if (t<off){ rs[t]+=rs[t+off]; rq[t]+=rq[t+off]; }
        __syncthreads();
    }
    if (t==0){ part[bid*2]=rs[0]; part[bid*2+1]=rq[0]; }
}

__global__ void k_gstd_final(const double* __restrict__ part, float* __restrict__ gstd)
{
    int t = threadIdx.x;
    if (t < 32){
        double s=0.0, s2=0.0;
        for (int j=0;j<8;j++){ s += part[(t*8+j)*2]; s2 += part[(t*8+j)*2+1]; }
        const double N = 262144.0;
        double var = (s2 - s*s/N) / (N - 1.0);
        gstd[t] = (float)sqrt(var < 0.0 ? 0.0 : var);
    }
}

__global__ void k_finalize(const float* __restrict__ ostat, const float* __restrict__ gstd,
                           const float* __restrict__ cwin, float* __restrict__ lov, float* __restrict__ hiv)
{
    int t = threadIdx.x;
    if (t < 32){
        float q25 = ostat[0] + 0.75f*(ostat[1]-ostat[0]);
        float q75 = ostat[2] + 0.25f*(ostat[3]-ostat[2]);
        float iqr = q75 - q25;
        float lo_b = q25 - 0.5f*iqr, hi_b = q75 + 0.5f*iqr;
        int c = t & 3;
        float m = fmaxf(fmaxf(cwin[0],cwin[1]), fmaxf(cwin[2],cwin[3]));
        float e0 = expf(cwin[0]-m), e1 = expf(cwin[1]-m), e2 = expf(cwin[2]-m), e3 = expf(cwin[3]-m);
        float smc = expf(cwin[c]-m) / (e0+e1+e2+e3);
        float g  = gstd[t];
        float gf = fminf(fmaxf(g*5.f, 0.5f), 2.f);
        float cf = fminf(fmaxf(smc*g*2.f, 0.8f), 1.2f);
        lov[t] = lo_b*gf*cf;
        hiv[t] = hi_b*gf*cf;
    }
}

__global__ void k_mask(const float* __restrict__ fused_in, const float* __restrict__ fb,
                       const float* __restrict__ lov, const float* __restrict__ hiv,
                       float* __restrict__ outp)
{
    int i = blockIdx.x*256 + threadIdx.x;
    float F = fmaxf(fused_in[i] + fb[0], 0.f);
    int b = i >> 18;
    float o = 0.f;
    #pragma unroll
    for (int c=0;c<4;c++){
        float lo = lov[b*4+c], hi = hiv[b*4+c];
        float n = (F - lo) / (hi - lo);
        n = fminf(fmaxf(n, 0.f), 1.f);
        o += 1.f/(1.f + expf(3.f - 6.f*n));
    }
    outp[i] = 0.25f * o;
}

// ---------------------------------------------------------------------------
extern "C" void kernel_launch(void* const* d_in, const int* in_sizes, int n_in,
                              void* d_out, int out_size, void* d_ws, size_t ws_size,
                              hipStream_t stream)
{
    const float* x  = (const float*)d_in[0];
    const float* w1 = (const float*)d_in[1];
    const float* b1 = (const float*)d_in[2];
    const float* w2 = (const float*)d_in[3];
    const float* b2 = (const float*)d_in[4];
    const float* w3 = (const float*)d_in[5];
    const float* b3 = (const float*)d_in[6];
    const float* fw = (const float*)d_in[7];
    const float* fb = (const float*)d_in[8];
    const float* cw = (const float*)d_in[9];
    float* out = (float*)d_out;
    char* ws = (char*)d_ws;

    size_t off = 0;
    auto take = [&](size_t bytes)->size_t{ size_t o = off; off += (bytes + 255) & ~(size_t)255; return o; };
    size_t o_h8     = take(256*4);
    size_t o_h8b    = take(1024*4);
    size_t o_histlo = take((size_t)4*65536*4);
    size_t o_c8     = take(4*4);
    size_t o_r8     = take(4*4);
    size_t o_c16    = take(4*4);
    size_t o_r16    = take(4*4);
    size_t o_os     = take(4*4);
    size_t o_part   = take(512*8);
    size_t o_gs     = take(32*4);
    size_t o_lo     = take(32*4);
    size_t o_hi     = take(32*4);
    // R1 (128 MiB): f2 full-batch during convs, then vs+vq during boxes.
    size_t o_R1     = take((size_t)NB*C3*HW*4);
    // R2 (64 MiB): f1 chunk during conv1/2, then fbuf (conv3 out) after.
    size_t o_R2     = take((size_t)NBC*C2*HW*4);

    float*    f2buf  = (float*)(ws + o_R1);
    float*    vsb    = (float*)(ws + o_R1);
    float*    vqb    = vsb + (size_t)NB*CF*HW;
    float*    f1     = (float*)(ws + o_R2);
    float*    fbuf   = (float*)(ws + o_R2);
    unsigned* hist8  = (unsigned*)(ws + o_h8);
    unsigned* hist8b = (unsigned*)(ws + o_h8b);
    unsigned* histlo = (unsigned*)(ws + o_histlo);
    int*      c8     = (int*)(ws + o_c8);
    int*      r8     = (int*)(ws + o_r8);
    int*      c16    = (int*)(ws + o_c16);
    int*      r16    = (int*)(ws + o_r16);
    float*    osv    = (float*)(ws + o_os);
    double*   part   = (double*)(ws + o_part);
    float*    gs     = (float*)(ws + o_gs);
    float*    lov    = (float*)(ws + o_lo);
    float*    hiv    = (float*)(ws + o_hi);

    // --- conv1+conv2 chunked (f2 accumulated full-batch), conv3 full-batch ---
    for (int ck = 0; ck < NB/NBC; ck++){
        const float* xb = x + (size_t)ck*NBC*CIN*HW;
        k_conv8<CIN,C2,true ><<<NBC*512,256,0,stream>>>(xb, w1, b1, f1);
        k_conv8<C2, C3,true ><<<NBC*256,256,0,stream>>>(f1, w2, b2,
                                                        f2buf + (size_t)ck*NBC*C3*HW);
    }
    k_conv8<C3, CF, false><<<NB*128,256,0,stream>>>(f2buf, w3, b3, fbuf);

    // --- global stds (independent of conv chain) ---
    k_gstd_part<<<256,256,0,stream>>>(x, part);
    k_gstd_final<<<1,256,0,stream>>>(part, gs);

    // --- multi-scale std maps (f2 region dead -> vs/vq alias it) ---
    hipMemsetAsync(out, 0, (size_t)NPIX*4, stream);
    const int vgrid = NB*CF*16, hgrid = NB*512;
    k_vbox<11><<<vgrid,256,0,stream>>>(fbuf, vsb, vqb);
    k_hbox<11><<<hgrid,256,0,stream>>>(vsb, vqb, out, fw, 0);
    k_vbox<25><<<vgrid,256,0,stream>>>(fbuf, vsb, vqb);
    k_hbox<25><<<hgrid,256,0,stream>>>(vsb, vqb, out, fw, 1);
    k_vbox<49><<<vgrid,256,0,stream>>>(fbuf, vsb, vqb);
    k_hbox<49><<<hgrid,256,0,stream>>>(vsb, vqb, out, fw, 2);

    // --- exact quantiles ---
    hipMemsetAsync(hist8,  0, 256*4,  stream);
    hipMemsetAsync(hist8b, 0, 1024*4, stream);
    hipMemsetAsync(histlo, 0, (size_t)4*65536*4, stream);
    k_h8    <<<2048,256,0,stream>>>(out, fb, hist8);
    k_scan8 <<<1,64,0,stream>>>(hist8, c8, r8);
    k_h8b   <<<2048,256,0,stream>>>(out, fb, c8, hist8b);
    k_scan8b<<<1,64,0,stream>>>(hist8b, c8, r8, c16, r16);
    k_h16   <<<2048,256,0,stream>>>(out, fb, c16, histlo);
    k_scan16<<<4,256,0,stream>>>(histlo, c16, r16, osv);

    // --- thresholds + mask (in-place on d_out) ---
    k_finalize<<<1,64,0,stream>>>(osv, gs, cw, lov, hiv);
    k_mask<<<NPIX/256,256,0,stream>>>(out, fb, lov, hiv, out);
}

// Round 7
// 905.917 us; speedup vs baseline: 1.3660x; 1.0119x over previous
//
#include <hip/hip_runtime.h>
#include <cmath>

#define HH 512
#define WW 512
#define NB 8
#define CIN 4
#define C2 32
#define C3 16
#define CF 8
#define HW (HH*WW)      /* 262144 */
#define NPIX (NB*HW)    /* 2097152 */
#define NBC 2           /* batches per conv chunk (workspace-fitted) */

__device__ __forceinline__ float lrelu_f(float v){ return v < 0.f ? 0.2f*v : v; }
__device__ __forceinline__ int reflect_i(int i){ int r = i < 0 ? -i : i; return r >= HH ? 2*HH - 2 - r : r; }

// ---------------------------------------------------------------------------
// Conv 3x3 (zero pad=1, OIHW). Thread = 2 rows x 4 cols x 8 oc. Weights in
// LDS (broadcast). Window loads: ONE aligned float4 + lane-neighbor shuffles
// (width 32) + exec-masked edge scalars -- replaces 24 scalar loads +
// per-element clamps per ci (round-6 post-mortem: that was the 44% VALU cap).
// ---------------------------------------------------------------------------
template<int Ci, int Co, bool LRELU>
__global__ __launch_bounds__(256) void k_conv8(const float* __restrict__ in,
                                               const float* __restrict__ wgt,
                                               const float* __restrict__ bias,
                                               float* __restrict__ outp)
{
    constexpr int NG = Co/8;
    __shared__ float wl[Co*Ci*9];
    __shared__ float bl[Co];
    for (int i = threadIdx.x; i < Co*Ci*9; i += 256) wl[i] = wgt[i];
    if (threadIdx.x < Co) bl[threadIdx.x] = bias[threadIdx.x];
    __syncthreads();

    int bid   = blockIdx.x;
    int local = bid % (NG*128);
    int b     = bid / (NG*128);
    int cb    = local & 3;            // 4 col-blocks of 128
    int rb    = (local >> 2) & 31;    // 32 row-blocks of 16
    int cg    = local >> 7;           // oc group
    int tid   = threadIdx.x;
    int lane  = tid & 31;
    int col   = cb*128 + lane*4;
    int row0  = rb*16  + (tid >> 5)*2;
    int co0   = cg*8;
    const float* inb = in + (size_t)b*Ci*HW;

    float acc[8][2][4];
    #pragma unroll
    for (int j=0;j<8;j++){
        float bv = bl[co0+j];
        #pragma unroll
        for (int r=0;r<2;r++)
            #pragma unroll
            for (int p=0;p<4;p++) acc[j][r][p] = bv;
    }

    #pragma unroll 2
    for (int ci=0; ci<Ci; ci++){
        float v[4][6];
        const float* inc = inb + (size_t)ci*HW;
        #pragma unroll
        for (int dy=0;dy<4;dy++){
            int hh = row0 + dy - 1;
            int hc = hh < 0 ? 0 : (hh > HH-1 ? HH-1 : hh);
            bool hok = (unsigned)hh < (unsigned)HH;
            const float* rowp = inc + hc*WW;
            float4 m = *(const float4*)(rowp + col);
            float lft = 0.f, rgt = 0.f;
            if (lane == 0  && col > 0)      lft = rowp[col-1];
            if (lane == 31 && col+4 < WW)   rgt = rowp[col+4];
            float v0 = __shfl_up(m.w, 1, 32);
            float v5 = __shfl_down(m.x, 1, 32);
            if (lane == 0)  v0 = lft;
            if (lane == 31) v5 = rgt;
            if (!hok){ m.x=0.f; m.y=0.f; m.z=0.f; m.w=0.f; v0=0.f; v5=0.f; }
            v[dy][0]=v0; v[dy][1]=m.x; v[dy][2]=m.y;
            v[dy][3]=m.z; v[dy][4]=m.w; v[dy][5]=v5;
        }
        #pragma unroll
        for (int j=0;j<8;j++){
            const float* wr = &wl[((co0+j)*Ci + ci)*9];
            float wj[9];
            #pragma unroll
            for (int q=0;q<9;q++) wj[q] = wr[q];
            #pragma unroll
            for (int dy=0;dy<3;dy++){
                #pragma unroll
                for (int dx=0;dx<3;dx++){
                    float wv = wj[dy*3+dx];
                    #pragma unroll
                    for (int r=0;r<2;r++)
                        #pragma unroll
                        for (int p=0;p<4;p++)
                            acc[j][r][p] = fmaf(v[dy+r][dx+p], wv, acc[j][r][p]);
                }
            }
        }
    }

    float* ob = outp + (size_t)b*Co*HW;
    #pragma unroll
    for (int j=0;j<8;j++){
        #pragma unroll
        for (int r=0;r<2;r++){
            float4 o;
            o.x = LRELU ? lrelu_f(acc[j][r][0]) : acc[j][r][0];
            o.y = LRELU ? lrelu_f(acc[j][r][1]) : acc[j][r][1];
            o.z = LRELU ? lrelu_f(acc[j][r][2]) : acc[j][r][2];
            o.w = LRELU ? lrelu_f(acc[j][r][3]) : acc[j][r][3];
            *(float4*)(ob + (size_t)(co0+j)*HW + (size_t)(row0+r)*WW + col) = o;
        }
    }
}

// ---------------------------------------------------------------------------
// FUSED multi-scale std-map kernel: V box (register sliding window, cols
// interleaved mod 32 for coalescing) -> LDS (swizzled) -> H box sliding ->
// variance/sqrt -> channel sum -> pow0.8 -> fused accumulate. vs/vq never
// touch HBM. Block = (batch, 256-col half, 16-row band); 512 blocks.
// ---------------------------------------------------------------------------
template<int WS, bool FIRST>
__global__ __launch_bounds__(256) void k_vhbox(const float* __restrict__ f,
                                               float* __restrict__ fused,
                                               const float* __restrict__ fwv, int sidx)
{
    constexpr int P    = WS/2;
    constexpr int SW   = ((256 + 2*P + 31)/32)*32;   // staged col count
    constexpr int SEGC = SW/32;                      // cols per thread (V phase)
    constexpr int SVW  = (SW + (SW>>4) + 3) | 1;     // LDS row stride (odd)
    constexpr int RSW  = 256 + 16 + 2;
    constexpr float inv = 1.f/((float)WS*(float)WS);

    __shared__ float sv[CF*SVW];
    __shared__ float sq[CF*SVW];
    __shared__ float resv[CF*RSW];

    int bid  = blockIdx.x;
    int band = bid & 31;
    int half = (bid >> 5) & 1;
    int b    = bid >> 6;
    int r0   = band*16;
    int c0   = half*256;
    int tid  = threadIdx.x;
    int ch   = tid >> 5;
    int seg  = tid & 31;

    const float* fp = f + (size_t)(b*CF + ch)*HW;

    // reflected global col for each owned staged col (k*32 + seg)
    int rc[SEGC];
    #pragma unroll
    for (int k = 0; k < SEGC; k++){
        int gc = c0 - P + k*32 + seg;
        gc = gc < 0 ? -gc : (gc > WW-1 ? 2*WW-2 - gc : gc);
        rc[k] = gc;
    }

    // init V window (rows r0-P .. r0+P, reflected)
    float vsr[SEGC], vqr[SEGC];
    #pragma unroll
    for (int k = 0; k < SEGC; k++){ vsr[k]=0.f; vqr[k]=0.f; }
    for (int dy = -P; dy <= P; dy++){
        const float* rp = fp + (size_t)reflect_i(r0+dy)*WW;
        #pragma unroll
        for (int k = 0; k < SEGC; k++){
            float v = rp[rc[k]];
            vsr[k] += v; vqr[k] = fmaf(v, v, vqr[k]);
        }
    }

    float fwb = fwv[sidx];

    for (int rr = 0; rr < 16; rr++){
        __syncthreads();                       // prev row's LDS reads done
        #pragma unroll
        for (int k = 0; k < SEGC; k++){
            int j = k*32 + seg; int sj = j + (j>>4);
            sv[ch*SVW + sj] = vsr[k];
            sq[ch*SVW + sj] = vqr[k];
        }
        // prefetch next slide rows (hides HBM/L3 latency under H phase)
        float ev[SEGC], lv[SEGC];
        if (rr < 15){
            const float* ep = fp + (size_t)reflect_i(r0+rr+1+P)*WW;
            const float* lp = fp + (size_t)reflect_i(r0+rr-P)*WW;
            #pragma unroll
            for (int k = 0; k < SEGC; k++){ ev[k]=ep[rc[k]]; lv[k]=lp[rc[k]]; }
        }
        __syncthreads();                       // V sums visible
        // H phase: this thread -> out cols [seg*8, seg*8+8) of channel ch
        int oc0 = seg*8;
        float S = 0.f, Q = 0.f;
        #pragma unroll
        for (int k = 0; k < WS; k++){
            int j = oc0 + k; int sj = j + (j>>4);
            S += sv[ch*SVW + sj];
            Q += sq[ch*SVW + sj];
        }
        float res[8];
        #pragma unroll
        for (int t = 0; t < 8; t++){
            float m  = S*inv, m2 = Q*inv;
            float var = fmaxf(fmaf(-m, m, m2), 1e-6f);
            res[t] = sqrtf(var);
            if (t < 7){
                int ja = oc0 + t + WS, jb = oc0 + t;
                S += sv[ch*SVW + ja + (ja>>4)] - sv[ch*SVW + jb + (jb>>4)];
                Q += sq[ch*SVW + ja + (ja>>4)] - sq[ch*SVW + jb + (jb>>4)];
            }
        }
        #pragma unroll
        for (int t = 0; t < 8; t++){
            int j = oc0 + t;
            resv[ch*RSW + j + (j>>4)] = res[t];
        }
        // apply V slide (VALU, overlaps with LDS latency)
        if (rr < 15){
            #pragma unroll
            for (int k = 0; k < SEGC; k++){
                vsr[k] += ev[k] - lv[k];
                vqr[k] = fmaf(ev[k], ev[k], vqr[k]);
                vqr[k] = fmaf(-lv[k], lv[k], vqr[k]);
            }
        }
        __syncthreads();                       // res visible
        int colI = tid;                        // one out col per thread
        float a = 0.f;
        #pragma unroll
        for (int cc = 0; cc < CF; cc++) a += resv[cc*RSW + colI + (colI>>4)];
        float val = fwb * powf(a*0.125f, 0.8f);
        size_t oi = ((size_t)b*HH + r0 + rr)*WW + c0 + colI;
        if (FIRST) fused[oi] = val; else fused[oi] += val;
    }
}

// ---------------------------------------------------------------------------
// Exact quantiles: 3-level radix (8/8/16 bits), LDS-privatized hot levels.
// ---------------------------------------------------------------------------
__global__ void k_h8(const float* __restrict__ fused, const float* __restrict__ fb,
                     unsigned* __restrict__ hist8)
{
    __shared__ unsigned lh[256];
    lh[threadIdx.x] = 0;
    __syncthreads();
    float fbv = fb[0];
    int i = blockIdx.x*256 + threadIdx.x;
    int stride = gridDim.x*256;
    for (; i < NPIX; i += stride){
        float v = fmaxf(fused[i] + fbv, 0.f);
        atomicAdd(&lh[__float_as_uint(v) >> 24], 1u);
    }
    __syncthreads();
    if (lh[threadIdx.x]) atomicAdd(&hist8[threadIdx.x], lh[threadIdx.x]);
}

__global__ void k_scan8(const unsigned* __restrict__ hist8,
                        int* __restrict__ cand8, int* __restrict__ rank8)
{
    if (threadIdx.x == 0){
        const unsigned RK[4] = {524287u, 524288u, 1572863u, 1572864u};
        unsigned cum = 0; int qi = 0;
        for (int b = 0; b < 256 && qi < 4; b++){
            unsigned cnt = hist8[b];
            while (qi < 4 && RK[qi] < cum + cnt){
                cand8[qi] = b; rank8[qi] = (int)(RK[qi] - cum); qi++;
            }
            cum += cnt;
        }
    }
}

__global__ void k_h8b(const float* __restrict__ fused, const float* __restrict__ fb,
                      const int* __restrict__ cand8, unsigned* __restrict__ hist8b)
{
    __shared__ unsigned lh[1024];
    for (int i = threadIdx.x; i < 1024; i += 256) lh[i] = 0;
    __syncthreads();
    float fbv = fb[0];
    int c0 = cand8[0], c1 = cand8[1], c2 = cand8[2], c3 = cand8[3];
    bool d1 = (c1 != c0);
    bool d2 = (c2 != c0) && (c2 != c1);
    bool d3 = (c3 != c0) && (c3 != c1) && (c3 != c2);
    int i = blockIdx.x*256 + threadIdx.x;
    int stride = gridDim.x*256;
    for (; i < NPIX; i += stride){
        unsigned u = __float_as_uint(fmaxf(fused[i] + fbv, 0.f));
        int hi = (int)(u >> 24);
        unsigned mid = (u >> 16) & 0xffu;
        if (hi == c0)       atomicAdd(&lh[mid],       1u);
        if (d1 && hi == c1) atomicAdd(&lh[256u+mid],  1u);
        if (d2 && hi == c2) atomicAdd(&lh[512u+mid],  1u);
        if (d3 && hi == c3) atomicAdd(&lh[768u+mid],  1u);
    }
    __syncthreads();
    for (int i = threadIdx.x; i < 1024; i += 256)
        if (lh[i]) atomicAdd(&hist8b[i], lh[i]);
}

__global__ void k_scan8b(const unsigned* __restrict__ hist8b,
                         const int* __restrict__ cand8, const int* __restrict__ rank8,
                         int* __restrict__ cand16, int* __restrict__ rank16)
{
    int qi = threadIdx.x;
    if (qi < 4){
        int slot = qi;
        for (int j = 0; j < qi; j++) if (cand8[j] == cand8[qi]){ slot = j; break; }
        const unsigned* h = hist8b + slot*256;
        unsigned k = (unsigned)rank8[qi], cum = 0;
        for (int b = 0; b < 256; b++){
            unsigned cnt = h[b];
            if (cnt && k >= cum && k < cum + cnt){
                cand16[qi] = (cand8[qi] << 8) | b;
                rank16[qi] = (int)(k - cum);
            }
            cum += cnt;
        }
    }
}

__global__ void k_h16(const float* __restrict__ fused, const float* __restrict__ fb,
                      const int* __restrict__ cand16, unsigned* __restrict__ histlo)
{
    float fbv = fb[0];
    int c0 = cand16[0], c1 = cand16[1], c2 = cand16[2], c3 = cand16[3];
    bool d1 = (c1 != c0);
    bool d2 = (c2 != c0) && (c2 != c1);
    bool d3 = (c3 != c0) && (c3 != c1) && (c3 != c2);
    int i = blockIdx.x*256 + threadIdx.x;
    int stride = gridDim.x*256;
    for (; i < NPIX; i += stride){
        unsigned u = __float_as_uint(fmaxf(fused[i] + fbv, 0.f));
        int hi = (int)(u >> 16);
        unsigned lo = u & 0xffffu;
        if (hi == c0)       atomicAdd(&histlo[lo],           1u);
        if (d1 && hi == c1) atomicAdd(&histlo[65536u + lo],  1u);
        if (d2 && hi == c2) atomicAdd(&histlo[131072u + lo], 1u);
        if (d3 && hi == c3) atomicAdd(&histlo[196608u + lo], 1u);
    }
}

__global__ void k_scan16(const unsigned* __restrict__ histlo,
                         const int* __restrict__ cand16, const int* __restrict__ rank16,
                         float* __restrict__ ostat)
{
    int qi = blockIdx.x;
    int slot = qi;
    for (int j = 0; j < qi; j++) if (cand16[j] == cand16[qi]){ slot = j; break; }
    const unsigned* hist = histlo + (size_t)slot*65536;
    __shared__ unsigned csum[256];
    __shared__ unsigned cbase[256];
    int t = threadIdx.x;
    unsigned s = 0;
    for (int i = 0; i < 256; i++) s += hist[t*256 + i];
    csum[t] = s;
    __syncthreads();
    if (t == 0){ unsigned run = 0; for (int i = 0; i < 256; i++){ cbase[i] = run; run += csum[i]; } }
    __syncthreads();
    unsigned k = (unsigned)rank16[qi];
    unsigned cum = cbase[t];
    for (int i = 0; i < 256; i++){
        unsigned cnt = hist[t*256 + i];
        if (cnt && k >= cum && k < cum + cnt)
            ostat[qi] = __uint_as_float(((unsigned)cand16[qi] << 16) | (unsigned)(t*256 + i));
        cum += cnt;
    }
}

// ---------------------------------------------------------------------------
// Global per-(b,c) std of x, ddof=1, double partial sums (deterministic).
// ---------------------------------------------------------------------------
__global__ void k_gstd_part(const float* __restrict__ x, double* __restrict__ part)
{
    int bid = blockIdx.x;
    int plane = bid >> 3, chunk = bid & 7;
    const float4* p4 = (const float4*)(x + (size_t)plane*HW + (size_t)chunk*32768);
    int t = threadIdx.x;
    double s=0.0, s2=0.0;
    for (int k=0;k<32;k++){
        float4 v = p4[k*256 + t];
        s  += (double)v.x + (double)v.y + (double)v.z + (double)v.w;
        s2 += (double)v.x*v.x + (double)v.y*v.y + (double)v.z*v.z + (double)v.w*v.w;
    }
    __shared__ double rs[256], rq[256];
    rs[t]=s; rq[t]=s2; __syncthreads();
    for (int off=128; off>0; off>>=1){
        if (t<off){ rs[t]+=rs[t+off]; rq[t]+=rq[t+off]; }
        __syncthreads();
    }
    if (t==0){ part[bid*2]=rs[0]; part[bid*2+1]=rq[0]; }
}

__global__ void k_gstd_final(const double* __restrict__ part, float* __restrict__ gstd)
{
    int t = threadIdx.x;
    if (t < 32){
        double s=0.0, s2=0.0;
        for (int j=0;j<8;j++){ s += part[(t*8+j)*2]; s2 += part[(t*8+j)*2+1]; }
        const double N = 262144.0;
        double var = (s2 - s*s/N) / (N - 1.0);
        gstd[t] = (float)sqrt(var < 0.0 ? 0.0 : var);
    }
}

__global__ void k_finalize(const float* __restrict__ ostat, const float* __restrict__ gstd,
                           const float* __restrict__ cwin, float* __restrict__ lov, float* __restrict__ hiv)
{
    int t = threadIdx.x;
    if (t < 32){
        float q25 = ostat[0] + 0.75f*(ostat[1]-ostat[0]);
        float q75 = ostat[2] + 0.25f*(ostat[3]-ostat[2]);
        float iqr = q75 - q25;
        float lo_b = q25 - 0.5f*iqr, hi_b = q75 + 0.5f*iqr;
        int c = t & 3;
        float m = fmaxf(fmaxf(cwin[0],cwin[1]), fmaxf(cwin[2],cwin[3]));
        float e0 = expf(cwin[0]-m), e1 = expf(cwin[1]-m), e2 = expf(cwin[2]-m), e3 = expf(cwin[3]-m);
        float smc = expf(cwin[c]-m) / (e0+e1+e2+e3);
        float g  = gstd[t];
        float gf = fminf(fmaxf(g*5.f, 0.5f), 2.f);
        float cf = fminf(fmaxf(smc*g*2.f, 0.8f), 1.2f);
        lov[t] = lo_b*gf*cf;
        hiv[t] = hi_b*gf*cf;
    }
}

__global__ void k_mask(const float* __restrict__ fused_in, const float* __restrict__ fb,
                       const float* __restrict__ lov, const float* __restrict__ hiv,
                       float* __restrict__ outp)
{
    int i = blockIdx.x*256 + threadIdx.x;
    float F = fmaxf(fused_in[i] + fb[0], 0.f);
    int b = i >> 18;
    float o = 0.f;
    #pragma unroll
    for (int c=0;c<4;c++){
        float lo = lov[b*4+c], hi = hiv[b*4+c];
        float n = (F - lo) / (hi - lo);
        n = fminf(fmaxf(n, 0.f), 1.f);
        o += 1.f/(1.f + expf(3.f - 6.f*n));
    }
    outp[i] = 0.25f * o;
}

// ---------------------------------------------------------------------------
extern "C" void kernel_launch(void* const* d_in, const int* in_sizes, int n_in,
                              void* d_out, int out_size, void* d_ws, size_t ws_size,
                              hipStream_t stream)
{
    const float* x  = (const float*)d_in[0];
    const float* w1 = (const float*)d_in[1];
    const float* b1 = (const float*)d_in[2];
    const float* w2 = (const float*)d_in[3];
    const float* b2 = (const float*)d_in[4];
    const float* w3 = (const float*)d_in[5];
    const float* b3 = (const float*)d_in[6];
    const float* fw = (const float*)d_in[7];
    const float* fb = (const float*)d_in[8];
    const float* cw = (const float*)d_in[9];
    float* out = (float*)d_out;
    char* ws = (char*)d_ws;

    size_t off = 0;
    auto take = [&](size_t bytes)->size_t{ size_t o = off; off += (bytes + 255) & ~(size_t)255; return o; };
    size_t o_h8     = take(256*4);
    size_t o_h8b    = take(1024*4);
    size_t o_histlo = take((size_t)4*65536*4);
    size_t o_c8     = take(4*4);
    size_t o_r8     = take(4*4);
    size_t o_c16    = take(4*4);
    size_t o_r16    = take(4*4);
    size_t o_os     = take(4*4);
    size_t o_part   = take(512*8);
    size_t o_gs     = take(32*4);
    size_t o_lo     = take(32*4);
    size_t o_hi     = take(32*4);
    // R1 (128 MiB): f2 full-batch during convs (dead after conv3).
    size_t o_R1     = take((size_t)NB*C3*HW*4);
    // R2 (64 MiB): f1 chunk during conv1/2, then fbuf (conv3 out, live through boxes).
    size_t o_R2     = take((size_t)NBC*C2*HW*4);

    float*    f2buf  = (float*)(ws + o_R1);
    float*    f1     = (float*)(ws + o_R2);
    float*    fbuf   = (float*)(ws + o_R2);
    unsigned* hist8  = (unsigned*)(ws + o_h8);
    unsigned* hist8b = (unsigned*)(ws + o_h8b);
    unsigned* histlo = (unsigned*)(ws + o_histlo);
    int*      c8     = (int*)(ws + o_c8);
    int*      r8     = (int*)(ws + o_r8);
    int*      c16    = (int*)(ws + o_c16);
    int*      r16    = (int*)(ws + o_r16);
    float*    osv    = (float*)(ws + o_os);
    double*   part   = (double*)(ws + o_part);
    float*    gs     = (float*)(ws + o_gs);
    float*    lov    = (float*)(ws + o_lo);
    float*    hiv    = (float*)(ws + o_hi);

    // --- conv1+conv2 chunked (f2 accumulated full-batch), conv3 full-batch ---
    for (int ck = 0; ck < NB/NBC; ck++){
        const float* xb = x + (size_t)ck*NBC*CIN*HW;
        k_conv8<CIN,C2,true ><<<NBC*512,256,0,stream>>>(xb, w1, b1, f1);
        k_conv8<C2, C3,true ><<<NBC*256,256,0,stream>>>(f1, w2, b2,
                                                        f2buf + (size_t)ck*NBC*C3*HW);
    }
    k_conv8<C3, CF, false><<<NB*128,256,0,stream>>>(f2buf, w3, b3, fbuf);

    // --- global stds (independent of conv chain) ---
    k_gstd_part<<<256,256,0,stream>>>(x, part);
    k_gstd_final<<<1,256,0,stream>>>(part, gs);

    // --- fused multi-scale std maps (no vs/vq round-trip, no memset) ---
    const int bgrid = NB*2*32;   // 512 blocks
    k_vhbox<11,true ><<<bgrid,256,0,stream>>>(fbuf, out, fw, 0);
    k_vhbox<25,false><<<bgrid,256,0,stream>>>(fbuf, out, fw, 1);
    k_vhbox<49,false><<<bgrid,256,0,stream>>>(fbuf, out, fw, 2);

    // --- exact quantiles ---
    hipMemsetAsync(hist8,  0, 256*4,  stream);
    hipMemsetAsync(hist8b, 0, 1024*4, stream);
    hipMemsetAsync(histlo, 0, (size_t)4*65536*4, stream);
    k_h8    <<<2048,256,0,stream>>>(out, fb, hist8);
    k_scan8 <<<1,64,0,stream>>>(hist8, c8, r8);
    k_h8b   <<<2048,256,0,stream>>>(out, fb, c8, hist8b);
    k_scan8b<<<1,64,0,stream>>>(hist8b, c8, r8, c16, r16);
    k_h16   <<<2048,256,0,stream>>>(out, fb, c16, histlo);
    k_scan16<<<4,256,0,stream>>>(histlo, c16, r16, osv);

    // --- thresholds + mask (in-place on d_out) ---
    k_finalize<<<1,64,0,stream>>>(osv, gs, cw, lov, hiv);
    k_mask<<<NPIX/256,256,0,stream>>>(out, fb, lov, hiv, out);
}